// Round 16
// baseline (158.159 us; speedup 1.0000x reference)
//
#include <hip/hip_runtime.h>
#include <hip/hip_bf16.h>

#define ALPHA 0.9f
#define BETA  0.85f
#define TSIM  50
#define BATCH 128
#define N0    1024
#define N1    2048
#define N2    2048
#define N3    512

// alpha^50, beta^50, 1/(alpha-beta)
#define A50   0.00515379f
#define B50   0.000295764f
#define INVAB 20.0f

typedef __attribute__((ext_vector_type(8))) short bf16x8;
typedef __attribute__((ext_vector_type(8))) unsigned short ushort8;
typedef __attribute__((ext_vector_type(4))) float f32x4;

#define GLOBAL_AS __attribute__((address_space(1)))
#define LDS_AS    __attribute__((address_space(3)))

// preprocessor repeat lists (t = literal timestep)
#define R32(X) X(0) X(1) X(2) X(3) X(4) X(5) X(6) X(7) X(8) X(9) X(10) X(11) \
               X(12) X(13) X(14) X(15) X(16) X(17) X(18) X(19) X(20) X(21)   \
               X(22) X(23) X(24) X(25) X(26) X(27) X(28) X(29) X(30) X(31)
#define R18(X) X(32) X(33) X(34) X(35) X(36) X(37) X(38) X(39) X(40) X(41)   \
               X(42) X(43) X(44) X(45) X(46) X(47) X(48) X(49)
#define R50(X) R32(X) R18(X)

#define DECLC(t)   float c##t = 0.f;
#define PROBELO(t) c##t += w * (float)((lo >> (t)) & 1u);
#define PROBEHI(t) c##t += w * (float)((hi >> ((t) - 32)) & 1u);
#define STEPT(t)                                                  \
    s = ALPHA * s + (base + c##t);                                \
    m = BETA * m + s;                                             \
    if (m - 1.f > 0.f) { a2 += (pa - pb) * INVAB; m = 0.f; }      \
    pa *= inva;                                                   \
    pb *= invb;

// ---------------------------------------------------------------------------
// Split-K fp32 tiled GEMM: Cp[z] = A(M, K-chunk z) @ B(chunk z, N).
// Partials + consumer reduce (round 6: atomicAdd reduction = 2x cost).
// ---------------------------------------------------------------------------
__global__ __launch_bounds__(256) void gemm_f32_splitk(const float* __restrict__ A,
                                                       const float* __restrict__ B,
                                                       float* __restrict__ Cp,
                                                       int M, int N, int K, int KC) {
    __shared__ float As[16][65];
    __shared__ float Bs[16][68];

    const int tid = threadIdx.x;
    const int tx  = tid % 16;
    const int ty  = tid / 16;
    const int bx  = blockIdx.x;
    const int by  = blockIdx.y;
    const int z   = blockIdx.z;

    float acc[4][4] = {};

    const int ar = tid / 4;
    const int ak = (tid % 4) * 4;
    const int br = tid / 16;
    const int bc = (tid % 16) * 4;

    const int kbeg = z * KC;
    for (int k0 = kbeg; k0 < kbeg + KC; k0 += 16) {
        float4 av = *(const float4*)&A[(size_t)(by * 64 + ar) * K + k0 + ak];
        As[ak + 0][ar] = av.x;
        As[ak + 1][ar] = av.y;
        As[ak + 2][ar] = av.z;
        As[ak + 3][ar] = av.w;
        float4 bv = *(const float4*)&B[(size_t)(k0 + br) * N + bx * 64 + bc];
        *(float4*)&Bs[br][bc] = bv;
        __syncthreads();

#pragma unroll
        for (int kk = 0; kk < 16; ++kk) {
            float a0 = As[kk][ty * 4 + 0];
            float a1 = As[kk][ty * 4 + 1];
            float a2 = As[kk][ty * 4 + 2];
            float a3 = As[kk][ty * 4 + 3];
            float b0 = Bs[kk][tx * 4 + 0];
            float b1 = Bs[kk][tx * 4 + 1];
            float b2 = Bs[kk][tx * 4 + 2];
            float b3 = Bs[kk][tx * 4 + 3];
            acc[0][0] += a0 * b0; acc[0][1] += a0 * b1; acc[0][2] += a0 * b2; acc[0][3] += a0 * b3;
            acc[1][0] += a1 * b0; acc[1][1] += a1 * b1; acc[1][2] += a1 * b2; acc[1][3] += a1 * b3;
            acc[2][0] += a2 * b0; acc[2][1] += a2 * b1; acc[2][2] += a2 * b2; acc[2][3] += a2 * b3;
            acc[3][0] += a3 * b0; acc[3][1] += a3 * b1; acc[3][2] += a3 * b2; acc[3][3] += a3 * b3;
        }
        __syncthreads();
    }

#pragma unroll
    for (int i = 0; i < 4; ++i) {
        float4 v = make_float4(acc[i][0], acc[i][1], acc[i][2], acc[i][3]);
        *(float4*)&Cp[((size_t)z * M + by * 64 + ty * 4 + i) * N + bx * 64 + tx * 4] = v;
    }
}

// ---------------------------------------------------------------------------
// Coalesced split-transpose: W1(K,N) fp32 -> Th,Tl (N,K) bf16 hi/lo.
// 128(k) x 32(n) tile; 16B stores fill full 128B lines (round-14 verified).
// ---------------------------------------------------------------------------
__global__ __launch_bounds__(256) void split_transpose_fast(const float* __restrict__ W,
                                                            __hip_bfloat16* __restrict__ Th,
                                                            __hip_bfloat16* __restrict__ Tl) {
    __shared__ float Wf[128][33];

    const int tid = threadIdx.x;
    const int n0  = blockIdx.x * 32;
    const int k0  = blockIdx.y * 128;

#pragma unroll
    for (int it = 0; it < 16; ++it) {
        const int idx = it * 256 + tid;
        const int kk  = idx >> 5;
        const int nn  = idx & 31;
        Wf[kk][nn] = W[(size_t)(k0 + kk) * N2 + n0 + nn];
    }
    __syncthreads();

    const int nl  = tid >> 3;
    const int oct = tid & 7;
#pragma unroll
    for (int half = 0; half < 2; ++half) {
        const int kb = half * 64 + oct * 8;
        ushort8 vh, vl;
#pragma unroll
        for (int u = 0; u < 8; ++u) {
            const float w = Wf[kb + u][nl];
            const __hip_bfloat16 hi = __float2bfloat16(w);
            const float lo = w - __bfloat162float(hi);
            const __hip_bfloat16 lb = __float2bfloat16(lo);
            vh[u] = *(const unsigned short*)&hi;
            vl[u] = *(const unsigned short*)&lb;
        }
        const size_t o = (size_t)(n0 + nl) * N1 + k0 + kb;
        *(ushort8*)&Th[o] = vh;
        *(ushort8*)&Tl[o] = vl;
    }
}

// ---------------------------------------------------------------------------
// Layer-0 simulate + classify (sums 4 split-K partials; deterministic
// per-(b,chunk) residual lists via wave ballot + LDS wave-count scan).
// ---------------------------------------------------------------------------
__global__ __launch_bounds__(256) void scan_l0_classify(const float* __restrict__ P0,
                                                        __hip_bfloat16* __restrict__ C0,
                                                        int* __restrict__ jlist0,
                                                        unsigned long long* __restrict__ mask0,
                                                        int* __restrict__ count0) {
    const int b     = blockIdx.x;
    const int chunk = blockIdx.y;
    const int tid   = threadIdx.x;
    const int j     = chunk * 256 + tid;
    const int lane  = tid & 63;
    const int wv    = tid >> 6;

    float h = 0.f;
#pragma unroll
    for (int z = 0; z < 4; ++z) h += P0[((size_t)z * BATCH + b) * N1 + j];

    float m = 0.f;
    unsigned long long mask = 0ull;
#pragma unroll
    for (int t = 0; t < TSIM; ++t) {
        m = BETA * m + h;
        if (m - 1.f > 0.f) { mask |= (1ull << t); m = 0.f; }
    }
    const unsigned long long FULL = (1ull << TSIM) - 1ull;
    C0[(size_t)b * N1 + j] = __float2bfloat16((mask == FULL) ? 1.f : 0.f);

    const bool has = (mask != 0ull) && (mask != FULL);
    const unsigned long long bal = __ballot(has);

    __shared__ int wcnt[4];
    if (lane == 0) wcnt[wv] = __popcll(bal);
    __syncthreads();
    int base = 0;
#pragma unroll
    for (int w = 0; w < 4; ++w)
        if (w < wv) base += wcnt[w];
    const int pos = base + __popcll(bal & ((1ull << lane) - 1ull));

    const size_t lbase = (size_t)(b * 8 + chunk) * 256;
    if (has) {
        jlist0[lbase + pos] = j;
        mask0[lbase + pos]  = mask;
    }
    if (tid == 0) count0[b * 8 + chunk] = wcnt[0] + wcnt[1] + wcnt[2] + wcnt[3];
}

// ---------------------------------------------------------------------------
// MFMA GEMM (BN=64, BM=128=M, BK=32; 4 waves stacked in M; WMT=2, WNT=4):
// Cp[z] = C0 @ (Bh+Bl)^T, split-K 8 (KC=256). A bf16 exact {0,1}.
// ---------------------------------------------------------------------------
__global__ __launch_bounds__(256) void gemm3_bn64(const __hip_bfloat16* __restrict__ A,
                                                  const __hip_bfloat16* __restrict__ Bh,
                                                  const __hip_bfloat16* __restrict__ Bl,
                                                  float* __restrict__ Cp, int KC) {
    __shared__ alignas(16) __hip_bfloat16 As[128 * 32];
    __shared__ alignas(16) __hip_bfloat16 Bhs[64 * 32];
    __shared__ alignas(16) __hip_bfloat16 Bls[64 * 32];

    constexpr int BK = 32;
    const int M = BATCH, N = N2, K = N1;

    const int tid  = threadIdx.x;
    const int wave = tid >> 6;
    const int lane = tid & 63;
    const int quad = lane >> 4;
    const int l16  = lane & 15;

    const int n0 = blockIdx.x * 64;
    const int z  = blockIdx.y;
    const int wm = wave * 32;

    f32x4 acc[2][4] = {};

    const __hip_bfloat16* agp[2];
    int aoff[2];
#pragma unroll
    for (int i = 0; i < 2; ++i) {
        const int c = i * 256 + tid;
        agp[i]  = A + (size_t)(c >> 2) * K + (c & 3) * 8;
        aoff[i] = c * 8;
    }
    const __hip_bfloat16* bhgp = Bh + (size_t)(n0 + (tid >> 2)) * K + (tid & 3) * 8;
    const __hip_bfloat16* blgp = Bl + (size_t)(n0 + (tid >> 2)) * K + (tid & 3) * 8;
    const int boff = tid * 8;

    const int kbeg = z * KC;
    for (int k0 = kbeg; k0 < kbeg + KC; k0 += BK) {
#pragma unroll
        for (int i = 0; i < 2; ++i)
            __builtin_amdgcn_global_load_lds((const GLOBAL_AS void*)(agp[i] + k0),
                                             (LDS_AS void*)&As[aoff[i]], 16, 0, 0);
        __builtin_amdgcn_global_load_lds((const GLOBAL_AS void*)(bhgp + k0),
                                         (LDS_AS void*)&Bhs[boff], 16, 0, 0);
        __builtin_amdgcn_global_load_lds((const GLOBAL_AS void*)(blgp + k0),
                                         (LDS_AS void*)&Bls[boff], 16, 0, 0);
        __syncthreads();

        bf16x8 af[2], bhf[4], blf[4];
#pragma unroll
        for (int i = 0; i < 2; ++i)
            af[i] = *(const bf16x8*)&As[(wm + i * 16 + l16) * BK + quad * 8];
#pragma unroll
        for (int j = 0; j < 4; ++j) {
            bhf[j] = *(const bf16x8*)&Bhs[(j * 16 + l16) * BK + quad * 8];
            blf[j] = *(const bf16x8*)&Bls[(j * 16 + l16) * BK + quad * 8];
        }
#pragma unroll
        for (int i = 0; i < 2; ++i)
#pragma unroll
            for (int j = 0; j < 4; ++j) {
                acc[i][j] = __builtin_amdgcn_mfma_f32_16x16x32_bf16(af[i], bhf[j], acc[i][j], 0, 0, 0);
                acc[i][j] = __builtin_amdgcn_mfma_f32_16x16x32_bf16(af[i], blf[j], acc[i][j], 0, 0, 0);
            }
        __syncthreads();
    }

    // C/D layout: col = lane&15, row = quad*4 + reg
#pragma unroll
    for (int i = 0; i < 2; ++i)
#pragma unroll
        for (int j = 0; j < 4; ++j)
#pragma unroll
            for (int r = 0; r < 4; ++r)
                Cp[((size_t)z * M + wm + i * 16 + quad * 4 + r) * N + n0 + j * 16 + l16] =
                    acc[i][j][r];
}

// ---------------------------------------------------------------------------
// Layer-1 fused drive + membrane scan + linear layer-2 projection.
// 50 named scalar accumulators + __launch_bounds__(256,2): the (256,2)
// register budget is what stopped the allocator from spilling (rounds 4-10:
// VGPR 36-68, h1 35-79us; round 11: out of top-5). Do not lower the bound.
// Sums 8 PB1 partials (gemm3 split-K 8).
// ---------------------------------------------------------------------------
__global__ __launch_bounds__(256, 2) void h1_scan_a2(const float* __restrict__ PB1,
                                                     const float* __restrict__ W1,
                                                     const int* __restrict__ jlist0,
                                                     const unsigned long long* __restrict__ mask0,
                                                     const int* __restrict__ count0,
                                                     float* __restrict__ A2) {
    const int b  = blockIdx.x;
    const int jc = blockIdx.y * 256 + threadIdx.x;

    float base = 0.f;
#pragma unroll
    for (int z = 0; z < 8; ++z) base += PB1[((size_t)z * BATCH + b) * N2 + jc];

    R50(DECLC)

    for (int c = 0; c < 8; ++c) {
        const int cnt      = count0[b * 8 + c];
        const size_t lbase = (size_t)(b * 8 + c) * 256;
        for (int e = 0; e < cnt; ++e) {
            const unsigned long long mk = mask0[lbase + e];
            const int j                 = jlist0[lbase + e];
            const float w               = W1[(size_t)j * N2 + jc];
            const unsigned lo = (unsigned)mk, hi = (unsigned)(mk >> 32);
            R32(PROBELO)
            R18(PROBEHI)
        }
    }

    float s = 0.f, m = 0.f, a2 = 0.f;
    float pa = A50, pb = B50;
    const float inva = 1.0f / ALPHA, invb = 1.0f / BETA;
    R50(STEPT)

    A2[(size_t)b * N2 + jc] = a2;
}

// ---------------------------------------------------------------------------
// Sum 8 split-K partials of A2@W2 -> final output (128 x 512).
// ---------------------------------------------------------------------------
__global__ __launch_bounds__(256) void reduce_out(const float* __restrict__ PB2,
                                                  float* __restrict__ out) {
    const int idx = blockIdx.x * 256 + threadIdx.x;
    float v = 0.f;
#pragma unroll
    for (int z = 0; z < 8; ++z) v += PB2[(size_t)z * (BATCH * N3) + idx];
    out[idx] = v;
}

extern "C" void kernel_launch(void* const* d_in, const int* in_sizes, int n_in,
                              void* d_out, int out_size, void* d_ws, size_t ws_size,
                              hipStream_t stream) {
    const float* inputs = (const float*)d_in[0];   // (128, 1024)
    const float* W0     = (const float*)d_in[1];   // (1024, 2048)
    const float* W1     = (const float*)d_in[2];   // (2048, 2048)
    const float* W2     = (const float*)d_in[3];   // (2048, 512)
    float* out = (float*)d_out;                    // (128, 512)

    // workspace layout (~40 MB)
    float* P0  = (float*)d_ws;                         // 4 x 128 x 2048   fp32
    float* PB1 = P0 + 4 * BATCH * N1;                  // 8 x 128 x 2048   fp32
    float* A2  = PB1 + 8 * BATCH * N2;                 // 128 x 2048       fp32
    float* PB2 = A2 + BATCH * N2;                      // 8 x 128 x 512    fp32
    unsigned long long* mk0 = (unsigned long long*)(PB2 + 8 * BATCH * N3);   // 128x8x256
    __hip_bfloat16* C0bf = (__hip_bfloat16*)(mk0 + BATCH * 8 * 256);         // 128 x 2048
    __hip_bfloat16* W1th = C0bf + (size_t)BATCH * N1;                        // 2048 x 2048
    __hip_bfloat16* W1tl = W1th + (size_t)N2 * N1;                           // 2048 x 2048
    int* jl0  = (int*)(W1tl + (size_t)N2 * N1);                              // 128 x 8 x 256
    int* cnt0 = jl0 + BATCH * 8 * 256;                                       // 128 x 8

    // 0. W1 -> transposed bf16 hi/lo pair
    split_transpose_fast<<<dim3(N2 / 32, N1 / 128), 256, 0, stream>>>(W1, W1th, W1tl);

    // 1. P0[z] = inputs @ W0 chunks   (128 x 1024 x 2048, split-K 4, fp32)
    gemm_f32_splitk<<<dim3(N1 / 64, BATCH / 64, 4), 256, 0, stream>>>(
        inputs, W0, P0, BATCH, N1, N0, N0 / 4);

    // 2. layer-0 simulate + classify -> C0 (bf16), residual lists
    scan_l0_classify<<<dim3(BATCH, N1 / 256), 256, 0, stream>>>(P0, C0bf, jl0, mk0, cnt0);

    // 3. PB1[z] = C0 @ W1 chunks      (128 x 2048 x 2048, split-K 8, MFMA BN=64)
    gemm3_bn64<<<dim3(N2 / 64, 8), 256, 0, stream>>>(C0bf, W1th, W1tl, PB1, N1 / 8);

    // 4. fused layer-1 drive + scan + linear layer-2 projection -> A2
    h1_scan_a2<<<dim3(BATCH, N2 / 256), 256, 0, stream>>>(
        PB1, W1, jl0, mk0, cnt0, A2);

    // 5. PB2[z] = A2 @ W2 chunks      (128 x 2048 x 512, split-K 8, fp32)
    gemm_f32_splitk<<<dim3(N3 / 64, BATCH / 64, 8), 256, 0, stream>>>(
        A2, W2, PB2, BATCH, N3, N2, N2 / 8);

    // 6. sum partials -> final membrane (128 x 512)
    reduce_out<<<(BATCH * N3) / 256, 256, 0, stream>>>(PB2, out);
}

// Round 17
// 146.337 us; speedup vs baseline: 1.0808x; 1.0808x over previous
//
#include <hip/hip_runtime.h>
#include <hip/hip_bf16.h>

#define ALPHA 0.9f
#define BETA  0.85f
#define TSIM  50
#define BATCH 128
#define N0    1024
#define N1    2048
#define N2    2048
#define N3    512

// alpha^50, beta^50, 1/(alpha-beta)
#define A50   0.00515379f
#define B50   0.000295764f
#define INVAB 20.0f

typedef __attribute__((ext_vector_type(8))) short bf16x8;
typedef __attribute__((ext_vector_type(8))) unsigned short ushort8;
typedef __attribute__((ext_vector_type(4))) float f32x4;

#define GLOBAL_AS __attribute__((address_space(1)))
#define LDS_AS    __attribute__((address_space(3)))

// preprocessor repeat lists (t = literal timestep)
#define R32(X) X(0) X(1) X(2) X(3) X(4) X(5) X(6) X(7) X(8) X(9) X(10) X(11) \
               X(12) X(13) X(14) X(15) X(16) X(17) X(18) X(19) X(20) X(21)   \
               X(22) X(23) X(24) X(25) X(26) X(27) X(28) X(29) X(30) X(31)
#define R18(X) X(32) X(33) X(34) X(35) X(36) X(37) X(38) X(39) X(40) X(41)   \
               X(42) X(43) X(44) X(45) X(46) X(47) X(48) X(49)
#define R50(X) R32(X) R18(X)

#define DECLC(t)   float c##t = 0.f;
#define PROBELO(t) c##t += w * (float)((lo >> (t)) & 1u);
#define PROBEHI(t) c##t += w * (float)((hi >> ((t) - 32)) & 1u);
#define STEPT(t)                                                  \
    s = ALPHA * s + (base + c##t);                                \
    m = BETA * m + s;                                             \
    if (m - 1.f > 0.f) { a2 += (pa - pb) * INVAB; m = 0.f; }      \
    pa *= inva;                                                   \
    pb *= invb;

// ---------------------------------------------------------------------------
// Split-K fp32 tiled GEMM: Cp[z] = A(M, K-chunk z) @ B(chunk z, N).
// Partials + consumer reduce (round 6: atomicAdd reduction = 2x cost).
// Round 16 lesson: do NOT lower split-K — block count beats partial traffic
// for these skinny GEMMs (partials are L2-resident anyway).
// ---------------------------------------------------------------------------
__global__ __launch_bounds__(256) void gemm_f32_splitk(const float* __restrict__ A,
                                                       const float* __restrict__ B,
                                                       float* __restrict__ Cp,
                                                       int M, int N, int K, int KC) {
    __shared__ float As[16][65];
    __shared__ float Bs[16][68];

    const int tid = threadIdx.x;
    const int tx  = tid % 16;
    const int ty  = tid / 16;
    const int bx  = blockIdx.x;
    const int by  = blockIdx.y;
    const int z   = blockIdx.z;

    float acc[4][4] = {};

    const int ar = tid / 4;
    const int ak = (tid % 4) * 4;
    const int br = tid / 16;
    const int bc = (tid % 16) * 4;

    const int kbeg = z * KC;
    for (int k0 = kbeg; k0 < kbeg + KC; k0 += 16) {
        float4 av = *(const float4*)&A[(size_t)(by * 64 + ar) * K + k0 + ak];
        As[ak + 0][ar] = av.x;
        As[ak + 1][ar] = av.y;
        As[ak + 2][ar] = av.z;
        As[ak + 3][ar] = av.w;
        float4 bv = *(const float4*)&B[(size_t)(k0 + br) * N + bx * 64 + bc];
        *(float4*)&Bs[br][bc] = bv;
        __syncthreads();

#pragma unroll
        for (int kk = 0; kk < 16; ++kk) {
            float a0 = As[kk][ty * 4 + 0];
            float a1 = As[kk][ty * 4 + 1];
            float a2 = As[kk][ty * 4 + 2];
            float a3 = As[kk][ty * 4 + 3];
            float b0 = Bs[kk][tx * 4 + 0];
            float b1 = Bs[kk][tx * 4 + 1];
            float b2 = Bs[kk][tx * 4 + 2];
            float b3 = Bs[kk][tx * 4 + 3];
            acc[0][0] += a0 * b0; acc[0][1] += a0 * b1; acc[0][2] += a0 * b2; acc[0][3] += a0 * b3;
            acc[1][0] += a1 * b0; acc[1][1] += a1 * b1; acc[1][2] += a1 * b2; acc[1][3] += a1 * b3;
            acc[2][0] += a2 * b0; acc[2][1] += a2 * b1; acc[2][2] += a2 * b2; acc[2][3] += a2 * b3;
            acc[3][0] += a3 * b0; acc[3][1] += a3 * b1; acc[3][2] += a3 * b2; acc[3][3] += a3 * b3;
        }
        __syncthreads();
    }

#pragma unroll
    for (int i = 0; i < 4; ++i) {
        float4 v = make_float4(acc[i][0], acc[i][1], acc[i][2], acc[i][3]);
        *(float4*)&Cp[((size_t)z * M + by * 64 + ty * 4 + i) * N + bx * 64 + tx * 4] = v;
    }
}

// ---------------------------------------------------------------------------
// Coalesced split-transpose: W1(K,N) fp32 -> Th,Tl (N,K) bf16 hi/lo.
// 128(k) x 32(n) tile; 16B stores fill full 128B lines (round-14 verified).
// ---------------------------------------------------------------------------
__global__ __launch_bounds__(256) void split_transpose_fast(const float* __restrict__ W,
                                                            __hip_bfloat16* __restrict__ Th,
                                                            __hip_bfloat16* __restrict__ Tl) {
    __shared__ float Wf[128][33];

    const int tid = threadIdx.x;
    const int n0  = blockIdx.x * 32;
    const int k0  = blockIdx.y * 128;

#pragma unroll
    for (int it = 0; it < 16; ++it) {
        const int idx = it * 256 + tid;
        const int kk  = idx >> 5;
        const int nn  = idx & 31;
        Wf[kk][nn] = W[(size_t)(k0 + kk) * N2 + n0 + nn];
    }
    __syncthreads();

    const int nl  = tid >> 3;
    const int oct = tid & 7;
#pragma unroll
    for (int half = 0; half < 2; ++half) {
        const int kb = half * 64 + oct * 8;
        ushort8 vh, vl;
#pragma unroll
        for (int u = 0; u < 8; ++u) {
            const float w = Wf[kb + u][nl];
            const __hip_bfloat16 hi = __float2bfloat16(w);
            const float lo = w - __bfloat162float(hi);
            const __hip_bfloat16 lb = __float2bfloat16(lo);
            vh[u] = *(const unsigned short*)&hi;
            vl[u] = *(const unsigned short*)&lb;
        }
        const size_t o = (size_t)(n0 + nl) * N1 + k0 + kb;
        *(ushort8*)&Th[o] = vh;
        *(ushort8*)&Tl[o] = vl;
    }
}

// ---------------------------------------------------------------------------
// Layer-0 simulate + classify (sums 8 split-K partials; deterministic
// per-(b,chunk) residual lists via wave ballot + LDS wave-count scan).
// ---------------------------------------------------------------------------
__global__ __launch_bounds__(256) void scan_l0_classify(const float* __restrict__ P0,
                                                        __hip_bfloat16* __restrict__ C0,
                                                        int* __restrict__ jlist0,
                                                        unsigned long long* __restrict__ mask0,
                                                        int* __restrict__ count0) {
    const int b     = blockIdx.x;
    const int chunk = blockIdx.y;
    const int tid   = threadIdx.x;
    const int j     = chunk * 256 + tid;
    const int lane  = tid & 63;
    const int wv    = tid >> 6;

    float h = 0.f;
#pragma unroll
    for (int z = 0; z < 8; ++z) h += P0[((size_t)z * BATCH + b) * N1 + j];

    float m = 0.f;
    unsigned long long mask = 0ull;
#pragma unroll
    for (int t = 0; t < TSIM; ++t) {
        m = BETA * m + h;
        if (m - 1.f > 0.f) { mask |= (1ull << t); m = 0.f; }
    }
    const unsigned long long FULL = (1ull << TSIM) - 1ull;
    C0[(size_t)b * N1 + j] = __float2bfloat16((mask == FULL) ? 1.f : 0.f);

    const bool has = (mask != 0ull) && (mask != FULL);
    const unsigned long long bal = __ballot(has);

    __shared__ int wcnt[4];
    if (lane == 0) wcnt[wv] = __popcll(bal);
    __syncthreads();
    int base = 0;
#pragma unroll
    for (int w = 0; w < 4; ++w)
        if (w < wv) base += wcnt[w];
    const int pos = base + __popcll(bal & ((1ull << lane) - 1ull));

    const size_t lbase = (size_t)(b * 8 + chunk) * 256;
    if (has) {
        jlist0[lbase + pos] = j;
        mask0[lbase + pos]  = mask;
    }
    if (tid == 0) count0[b * 8 + chunk] = wcnt[0] + wcnt[1] + wcnt[2] + wcnt[3];
}

// ---------------------------------------------------------------------------
// MFMA GEMM (BN=64, BM=128=M, BK=32; 4 waves stacked in M; WMT=2, WNT=4):
// Cp[z] = C0 @ (Bh+Bl)^T, split-K 16 (KC=128, 512 blocks — round-16 lesson:
// keep block count high). A bf16 exact {0,1}.
// ---------------------------------------------------------------------------
__global__ __launch_bounds__(256) void gemm3_bn64(const __hip_bfloat16* __restrict__ A,
                                                  const __hip_bfloat16* __restrict__ Bh,
                                                  const __hip_bfloat16* __restrict__ Bl,
                                                  float* __restrict__ Cp, int KC) {
    __shared__ alignas(16) __hip_bfloat16 As[128 * 32];
    __shared__ alignas(16) __hip_bfloat16 Bhs[64 * 32];
    __shared__ alignas(16) __hip_bfloat16 Bls[64 * 32];

    constexpr int BK = 32;
    const int M = BATCH, N = N2, K = N1;

    const int tid  = threadIdx.x;
    const int wave = tid >> 6;
    const int lane = tid & 63;
    const int quad = lane >> 4;
    const int l16  = lane & 15;

    const int n0 = blockIdx.x * 64;
    const int z  = blockIdx.y;
    const int wm = wave * 32;

    f32x4 acc[2][4] = {};

    const __hip_bfloat16* agp[2];
    int aoff[2];
#pragma unroll
    for (int i = 0; i < 2; ++i) {
        const int c = i * 256 + tid;
        agp[i]  = A + (size_t)(c >> 2) * K + (c & 3) * 8;
        aoff[i] = c * 8;
    }
    const __hip_bfloat16* bhgp = Bh + (size_t)(n0 + (tid >> 2)) * K + (tid & 3) * 8;
    const __hip_bfloat16* blgp = Bl + (size_t)(n0 + (tid >> 2)) * K + (tid & 3) * 8;
    const int boff = tid * 8;

    const int kbeg = z * KC;
    for (int k0 = kbeg; k0 < kbeg + KC; k0 += BK) {
#pragma unroll
        for (int i = 0; i < 2; ++i)
            __builtin_amdgcn_global_load_lds((const GLOBAL_AS void*)(agp[i] + k0),
                                             (LDS_AS void*)&As[aoff[i]], 16, 0, 0);
        __builtin_amdgcn_global_load_lds((const GLOBAL_AS void*)(bhgp + k0),
                                         (LDS_AS void*)&Bhs[boff], 16, 0, 0);
        __builtin_amdgcn_global_load_lds((const GLOBAL_AS void*)(blgp + k0),
                                         (LDS_AS void*)&Bls[boff], 16, 0, 0);
        __syncthreads();

        bf16x8 af[2], bhf[4], blf[4];
#pragma unroll
        for (int i = 0; i < 2; ++i)
            af[i] = *(const bf16x8*)&As[(wm + i * 16 + l16) * BK + quad * 8];
#pragma unroll
        for (int j = 0; j < 4; ++j) {
            bhf[j] = *(const bf16x8*)&Bhs[(j * 16 + l16) * BK + quad * 8];
            blf[j] = *(const bf16x8*)&Bls[(j * 16 + l16) * BK + quad * 8];
        }
#pragma unroll
        for (int i = 0; i < 2; ++i)
#pragma unroll
            for (int j = 0; j < 4; ++j) {
                acc[i][j] = __builtin_amdgcn_mfma_f32_16x16x32_bf16(af[i], bhf[j], acc[i][j], 0, 0, 0);
                acc[i][j] = __builtin_amdgcn_mfma_f32_16x16x32_bf16(af[i], blf[j], acc[i][j], 0, 0, 0);
            }
        __syncthreads();
    }

    // C/D layout: col = lane&15, row = quad*4 + reg
#pragma unroll
    for (int i = 0; i < 2; ++i)
#pragma unroll
        for (int j = 0; j < 4; ++j)
#pragma unroll
            for (int r = 0; r < 4; ++r)
                Cp[((size_t)z * M + wm + i * 16 + quad * 4 + r) * N + n0 + j * 16 + l16] =
                    acc[i][j][r];
}

// ---------------------------------------------------------------------------
// Layer-1 fused drive + membrane scan + linear layer-2 projection.
// 50 named scalar accumulators + __launch_bounds__(256,2): the (256,2)
// register budget is what stopped the allocator from spilling (rounds 4-10:
// VGPR 36-68, h1 35-79us; round 11: out of top-5). Do not lower the bound.
// Sums 16 PB1 partials (gemm3 split-K 16).
// ---------------------------------------------------------------------------
__global__ __launch_bounds__(256, 2) void h1_scan_a2(const float* __restrict__ PB1,
                                                     const float* __restrict__ W1,
                                                     const int* __restrict__ jlist0,
                                                     const unsigned long long* __restrict__ mask0,
                                                     const int* __restrict__ count0,
                                                     float* __restrict__ A2) {
    const int b  = blockIdx.x;
    const int jc = blockIdx.y * 256 + threadIdx.x;

    float base = 0.f;
#pragma unroll
    for (int z = 0; z < 16; ++z) base += PB1[((size_t)z * BATCH + b) * N2 + jc];

    R50(DECLC)

    for (int c = 0; c < 8; ++c) {
        const int cnt      = count0[b * 8 + c];
        const size_t lbase = (size_t)(b * 8 + c) * 256;
        for (int e = 0; e < cnt; ++e) {
            const unsigned long long mk = mask0[lbase + e];
            const int j                 = jlist0[lbase + e];
            const float w               = W1[(size_t)j * N2 + jc];
            const unsigned lo = (unsigned)mk, hi = (unsigned)(mk >> 32);
            R32(PROBELO)
            R18(PROBEHI)
        }
    }

    float s = 0.f, m = 0.f, a2 = 0.f;
    float pa = A50, pb = B50;
    const float inva = 1.0f / ALPHA, invb = 1.0f / BETA;
    R50(STEPT)

    A2[(size_t)b * N2 + jc] = a2;
}

// ---------------------------------------------------------------------------
// Sum 16 split-K partials of A2@W2 -> final output (128 x 512).
// ---------------------------------------------------------------------------
__global__ __launch_bounds__(256) void reduce_out(const float* __restrict__ PB2,
                                                  float* __restrict__ out) {
    const int idx = blockIdx.x * 256 + threadIdx.x;
    float v = 0.f;
#pragma unroll
    for (int z = 0; z < 16; ++z) v += PB2[(size_t)z * (BATCH * N3) + idx];
    out[idx] = v;
}

extern "C" void kernel_launch(void* const* d_in, const int* in_sizes, int n_in,
                              void* d_out, int out_size, void* d_ws, size_t ws_size,
                              hipStream_t stream) {
    const float* inputs = (const float*)d_in[0];   // (128, 1024)
    const float* W0     = (const float*)d_in[1];   // (1024, 2048)
    const float* W1     = (const float*)d_in[2];   // (2048, 2048)
    const float* W2     = (const float*)d_in[3];   // (2048, 512)
    float* out = (float*)d_out;                    // (128, 512)

    // workspace layout (~51 MB) — round-15 best-path structure verbatim
    float* P0  = (float*)d_ws;                         // 8 x 128 x 2048   fp32
    float* PB1 = P0 + 8 * BATCH * N1;                  // 16 x 128 x 2048  fp32
    float* A2  = PB1 + 16 * BATCH * N2;                // 128 x 2048       fp32
    float* PB2 = A2 + BATCH * N2;                      // 16 x 128 x 512   fp32
    unsigned long long* mk0 = (unsigned long long*)(PB2 + 16 * BATCH * N3);  // 128x8x256
    __hip_bfloat16* C0bf = (__hip_bfloat16*)(mk0 + BATCH * 8 * 256);         // 128 x 2048
    __hip_bfloat16* W1th = C0bf + (size_t)BATCH * N1;                        // 2048 x 2048
    __hip_bfloat16* W1tl = W1th + (size_t)N2 * N1;                           // 2048 x 2048
    int* jl0  = (int*)(W1tl + (size_t)N2 * N1);                              // 128 x 8 x 256
    int* cnt0 = jl0 + BATCH * 8 * 256;                                       // 128 x 8

    // 0. W1 -> transposed bf16 hi/lo pair
    split_transpose_fast<<<dim3(N2 / 32, N1 / 128), 256, 0, stream>>>(W1, W1th, W1tl);

    // 1. P0[z] = inputs @ W0 chunks   (128 x 1024 x 2048, split-K 8, fp32)
    gemm_f32_splitk<<<dim3(N1 / 64, BATCH / 64, 8), 256, 0, stream>>>(
        inputs, W0, P0, BATCH, N1, N0, N0 / 8);

    // 2. layer-0 simulate + classify -> C0 (bf16), residual lists
    scan_l0_classify<<<dim3(BATCH, N1 / 256), 256, 0, stream>>>(P0, C0bf, jl0, mk0, cnt0);

    // 3. PB1[z] = C0 @ W1 chunks      (128 x 2048 x 2048, split-K 16, MFMA BN=64)
    gemm3_bn64<<<dim3(N2 / 64, 16), 256, 0, stream>>>(C0bf, W1th, W1tl, PB1, N1 / 16);

    // 4. fused layer-1 drive + scan + linear layer-2 projection -> A2
    h1_scan_a2<<<dim3(BATCH, N2 / 256), 256, 0, stream>>>(
        PB1, W1, jl0, mk0, cnt0, A2);

    // 5. PB2[z] = A2 @ W2 chunks      (128 x 2048 x 512, split-K 16, fp32)
    gemm_f32_splitk<<<dim3(N3 / 64, BATCH / 64, 16), 256, 0, stream>>>(
        A2, W2, PB2, BATCH, N3, N2, N2 / 16);

    // 6. sum partials -> final membrane (128 x 512)
    reduce_out<<<(BATCH * N3) / 256, 256, 0, stream>>>(PB2, out);
}